// Round 6
// baseline (359.012 us; speedup 1.0000x reference)
//
#include <hip/hip_runtime.h>
#include <math.h>

#define W 1024
#define H 768
#define PIX (W*H)          // 786432
#define NIMG 4
#define SNUM 131072
#define BPI 3072           // preprocessing blocks per image, 256 pixels each
#define NB (NIMG*BPI)      // 12288
#define GRID_L 2048        // loss blocks total
#define MASKV (-1e-8f)

// counter layout in ctrs (each on its own 64B line): ecnt[i] at i*16,
// vcnt[i] at (4+i)*16, ticket at 8*16. 144 u32 total.
#define CTR_E(i)  ((i)*16)
#define CTR_V(i)  ((4+(i))*16)
#define CTR_TKT   (8*16)

__device__ __forceinline__ void sobel_g(const float* __restrict__ img, int y, int x,
                                        float& gx, float& gy) {
    const float* r0 = img + (y - 1) * W + x;
    const float* r1 = r0 + W;
    const float* r2 = r1 + W;
    float a00 = r0[-1], a01 = r0[0], a02 = r0[1];
    float a10 = r1[-1],              a12 = r1[1];
    float a20 = r2[-1], a21 = r2[0], a22 = r2[1];
    gx = (a02 - a00) + 2.f * (a12 - a10) + (a22 - a20);
    gy = (a00 - a20) + 2.f * (a01 - a21) + (a02 - a22);
}

// ---- K0: Sobel magnitude + block max + pack {inp,tgt} + valid bits/counts ----
__global__ void prep_kernel(const float* __restrict__ inputs,
                            const float* __restrict__ targets,
                            const float* __restrict__ images,
                            float2* __restrict__ pairIT,
                            unsigned long long* __restrict__ vBits,
                            float* __restrict__ blockmax,
                            int* __restrict__ blkV,
                            unsigned* __restrict__ ctrs) {
    int b = blockIdx.x, t = threadIdx.x;
    if (b == 0 && t < 144) ctrs[t] = 0;            // zero ecnt/vcnt/ticket
    int i = b / BPI, bLoc = b - i * BPI;
    int gp = bLoc * 256 + t;
    int y = gp >> 10, x = gp & (W - 1);
    const float* img = images + (size_t)i * 3 * PIX;   // channel 0
    float e = 0.f;
    if (y >= 1 && y <= H - 2 && x >= 1 && x <= W - 2) {
        float gx, gy;
        sobel_g(img, y, x, gx, gy);
        e = sqrtf(gx * gx + gy * gy);
    }
    size_t off = (size_t)i * PIX + gp;
    float inv = inputs[off], tgv = targets[off];
    pairIT[off] = make_float2(inv, tgv);
    unsigned long long m = __ballot(tgv > MASKV);
    __shared__ float sm[256];
    __shared__ int sc[4];
    if ((t & 63) == 0) { vBits[off >> 6] = m; sc[t >> 6] = __popcll(m); }
    sm[t] = e;
    __syncthreads();
    for (int o = 128; o > 0; o >>= 1) {
        if (t < o) sm[t] = fmaxf(sm[t], sm[t + o]);
        __syncthreads();
    }
    if (t == 0) { blockmax[b] = sm[0]; blkV[b] = sc[0] + sc[1] + sc[2] + sc[3]; }
}

// ---- K1: redundant thr/vtot reduce + edge compaction (block-atomic base) ----
__global__ void compact_kernel(const float* __restrict__ images,
                               const float* __restrict__ blockmax,
                               const int* __restrict__ blkV,
                               const unsigned long long* __restrict__ vBits,
                               float2* __restrict__ anchorC, int* __restrict__ compV,
                               unsigned* __restrict__ ctrs, int* __restrict__ vtotG) {
    int b = blockIdx.x, t = threadIdx.x;
    int i = b / BPI, bLoc = b - i * BPI;

    // redundant per-block reduce of blockmax (max) and blkV (sum): 3072 entries each, L2-hot
    __shared__ float sf[256];
    __shared__ int si[256];
    const float* bm = blockmax + i * BPI;
    const int* bv = blkV + i * BPI;
    float mx = 0.f; int sv = 0;
#pragma unroll
    for (int k = 0; k < 12; k++) { mx = fmaxf(mx, bm[t + k * 256]); sv += bv[t + k * 256]; }
    sf[t] = mx; si[t] = sv;
    __syncthreads();
    for (int o = 128; o > 0; o >>= 1) {
        if (t < o) { sf[t] = fmaxf(sf[t], sf[t + o]); si[t] += si[t + o]; }
        __syncthreads();
    }
    float thr = 0.1f * sf[0];
    int vtot = si[0];
    if (bLoc == 0 && t == 0) vtotG[i] = vtot;

    // Sobel recompute for this block's 256 pixels
    int gp = bLoc * 256 + t;
    int y = gp >> 10, x = gp & (W - 1);
    const float* img = images + (size_t)i * 3 * PIX;
    float e = 0.f, gx = 0.f, gy = 0.f;
    bool inner = (y >= 1 && y <= H - 2 && x >= 1 && x <= W - 2);
    if (inner) { sobel_g(img, y, x, gx, gy); e = sqrtf(gx * gx + gy * gy); }
    bool isE = (e >= thr);                       // border e=0: matches padded ref

    int lane = t & 63, w = t >> 6;
    unsigned long long mE = __ballot(isE);
    __shared__ int sW[4];
    __shared__ int sBaseE;
    if (lane == 0) sW[w] = __popcll(mE);
    __syncthreads();
    if (t == 0) {
        int c0 = sW[0], c1 = sW[1], c2 = sW[2], c3 = sW[3];
        sW[0] = 0; sW[1] = c0; sW[2] = c0 + c1; sW[3] = c0 + c1 + c2;
        sBaseE = (int)atomicAdd(&ctrs[CTR_E(i)], (unsigned)(c0 + c1 + c2 + c3));
    }
    __syncthreads();
    if (isE) {
        float th = inner ? atan2f(gy, gx) : 0.f;
        int rank = sBaseE + sW[w] + __popcll(mE & ((1ull << lane) - 1ull));
        anchorC[(size_t)i * PIX + rank] = make_float2(__int_as_float(gp), th);
    }

    if (vtot < PIX) {                            // general path; data here is all-valid
        size_t woff = ((size_t)i * PIX + bLoc * 256) >> 6;
        unsigned long long mV = vBits[woff + w];
        bool isV = (mV >> lane) & 1;
        __shared__ int sWV[4];
        __shared__ int sBaseV;
        if (lane == 0) sWV[w] = __popcll(mV);
        __syncthreads();
        if (t == 0) {
            int c0 = sWV[0], c1 = sWV[1], c2 = sWV[2], c3 = sWV[3];
            sWV[0] = 0; sWV[1] = c0; sWV[2] = c0 + c1; sWV[3] = c0 + c1 + c2;
            sBaseV = (int)atomicAdd(&ctrs[CTR_V(i)], (unsigned)(c0 + c1 + c2 + c3));
        }
        __syncthreads();
        if (isV) {
            int rank = sBaseV + sWV[w] + __popcll(mV & ((1ull << lane) - 1ull));
            compV[(size_t)i * PIX + rank] = gp;
        }
    }
}

// ---- K2: loss + merged ticket finalizer ----
__device__ __forceinline__ void pair_term(float2 a, float2 b, float& eqs, float& uns) {
    float cm = ((a.y > MASKV) ? 1.f : 0.f) * ((b.y > MASKV) ? 1.f : 0.f);
    float ratio = (a.y + 1e-6f) / (b.y + 1e-6f);
    const float HIv = 1.03f;
    const float LOv = (float)(1.0 / 1.03);
    bool eq = (ratio < HIv) && (ratio > LOv);
    if (eq) {
        float d = a.x - b.x;
        eqs += d * d * cm;
    } else {
        float label = ((ratio >= HIv) ? 1.f : 0.f) + ((ratio <= LOv) ? -1.f : 0.f);
        uns += log1pf(expf((b.x - a.x) * label)) * cm;
    }
}

__global__ void loss_kernel(const float2* __restrict__ pairIT,
                            const float2* __restrict__ anchorC,
                            const int* __restrict__ compV,
                            const unsigned* __restrict__ ctrs_ro,
                            const int* __restrict__ vtotG,
                            const int* __restrict__ ra, const int* __restrict__ rd,
                            const int* __restrict__ rp,
                            float2* __restrict__ partials,
                            unsigned* __restrict__ ctrs,
                            float* __restrict__ out) {
    int i = blockIdx.y, t = threadIdx.x;
    int s = blockIdx.x * 256 + t;
    int bFlat = i * 512 + blockIdx.x;
    const float2* pIT = pairIT + (size_t)i * PIX;
    int eT = (int)ctrs_ro[CTR_E(i)];             // etot from compaction counter
    int vT = vtotG[i];
    int minlen = (eT > 0) ? eT : 1;              // eT>=1 always (emax pixel passes thr)
    int nval = (vT > 0) ? vT : 1;

    int j = ra[(size_t)i * SNUM + s] % minlen;
    float2 ac = anchorC[(size_t)i * PIX + j];    // one 8B line: pixel + theta
    int anchor = __float_as_int(ac.x);
    float sv = sinf(ac.y), cv = cosf(ac.y);
    int row_a = anchor >> 10, col_a = anchor & (W - 1);

    int pix4[4];
#pragma unroll
    for (int k = 0; k < 4; k++) {
        int r = rd[((size_t)i * 4 + k) * SNUM + s];
        float dist = ((float)r + 2.0f) * ((k < 2) ? -1.f : 1.f);
        int cc = col_a + (int)rintf(dist * cv);  // round-half-even = jnp.round
        int rr = row_a + (int)rintf(dist * sv);
        cc = min(max(cc, 0), W - 1);
        rr = min(max(rr, 0), H - 1);
        pix4[k] = (rr << 10) | cc;
    }
    int2 rr2 = *(const int2*)(rp + (size_t)i * 2 * SNUM + 2 * s);
    int r0 = rr2.x % nval, r1 = rr2.y % nval;
    bool ident = (vT == PIX) || (vT == 0);       // identity compaction cases
    int A = ident ? r0 : compV[(size_t)i * PIX + r0];
    int B = ident ? r1 : compV[(size_t)i * PIX + r1];

    float2 a0 = pIT[pix4[0]], a1 = pIT[pix4[1]], a2 = pIT[pix4[2]], a3 = pIT[pix4[3]];
    float2 b0 = pIT[A], b1 = pIT[B];
    float eqs = 0.f, uns = 0.f;
    pair_term(a0, a1, eqs, uns);
    pair_term(a1, a2, eqs, uns);
    pair_term(a2, a3, eqs, uns);
    pair_term(b0, b1, eqs, uns);

    __shared__ float sEq[256], sUn[256];
    __shared__ int sLast;
    sEq[t] = eqs; sUn[t] = uns;
    __syncthreads();
    for (int o = 128; o > 0; o >>= 1) {
        if (t < o) { sEq[t] += sEq[t + o]; sUn[t] += sUn[t + o]; }
        __syncthreads();
    }
    if (t == 0) {
        partials[bFlat] = make_float2(sEq[0], sUn[0]);
        __threadfence();                         // publish partials device-wide
        unsigned r = atomicAdd(&ctrs[CTR_TKT], 1u);
        sLast = (r == GRID_L - 1) ? 1 : 0;
    }
    __syncthreads();
    if (sLast) {                                 // last-arriving block reduces
        __threadfence();
        double acc = 0.0;
#pragma unroll
        for (int k = 0; k < 8; k++) {
            float2 p = partials[t + k * 256];
            acc += (double)p.x + (double)p.y;
        }
        __shared__ double sDr[256];
        sDr[t] = acc;
        __syncthreads();
        for (int o = 128; o > 0; o >>= 1) {
            if (t < o) sDr[t] += sDr[t + o];
            __syncthreads();
        }
        if (t == 0) {
            double denom = 4.0 * (double)SNUM;   // each mean over 4*S terms; ALPHA=1
            out[0] = (float)(sDr[0] / denom / (double)NIMG);
        }
    }
}

extern "C" void kernel_launch(void* const* d_in, const int* in_sizes, int n_in,
                              void* d_out, int out_size, void* d_ws, size_t ws_size,
                              hipStream_t stream) {
    const float* inputs  = (const float*)d_in[0];
    const float* targets = (const float*)d_in[1];
    const float* images  = (const float*)d_in[2];
    const int* ra = (const int*)d_in[3];
    const int* rd = (const int*)d_in[4];
    const int* rp = (const int*)d_in[5];
    float* out = (float*)d_out;

    char* ws = (char*)d_ws;
    unsigned* ctrs     = (unsigned*)ws;                    // 144 u32 (64B-spread counters)
    int*      vtotG    = (int*)(ws + 1024);                // [4]
    float*    blockmax = (float*)(ws + 2048);              // [12288] = 48KB
    int*      blkV     = (int*)(ws + 51200);               // [12288] = 48KB
    float2*   partials = (float2*)(ws + 100352);           // [2048] = 16KB
    unsigned long long* vBits = (unsigned long long*)(ws + 131072);   // 384KB
    float2*   pairIT   = (float2*)(ws + 1048576);          // 25.2MB
    float2*   anchorC  = (float2*)(ws + 26214400);         // 25.2MB (worst case)
    int*      compV    = (int*)(ws + 51380224);            // 12.6MB
    // total ~61MB; every word written before read -> no memset needed

    prep_kernel<<<NB, 256, 0, stream>>>(inputs, targets, images,
                                        pairIT, vBits, blockmax, blkV, ctrs);
    compact_kernel<<<NB, 256, 0, stream>>>(images, blockmax, blkV, vBits,
                                           anchorC, compV, ctrs, vtotG);
    loss_kernel<<<dim3(512, NIMG), 256, 0, stream>>>(pairIT, anchorC, compV,
                                                     ctrs, vtotG, ra, rd, rp,
                                                     partials, ctrs, out);
}

// Round 7
// 187.149 us; speedup vs baseline: 1.9183x; 1.9183x over previous
//
#include <hip/hip_runtime.h>
#include <math.h>

#define W 1024
#define H 768
#define PIX (W*H)          // 786432
#define NIMG 4
#define SNUM 131072
#define BPI 3072           // blocks per image, 256 pixels each
#define NB (NIMG*BPI)      // 12288
#define MASKV (-1e-8f)

__device__ __forceinline__ void sobel_g(const float* __restrict__ img, int y, int x,
                                        float& gx, float& gy) {
    const float* r0 = img + (y - 1) * W + x;
    const float* r1 = r0 + W;
    const float* r2 = r1 + W;
    float a00 = r0[-1], a01 = r0[0], a02 = r0[1];
    float a10 = r1[-1],              a12 = r1[1];
    float a20 = r2[-1], a21 = r2[0], a22 = r2[1];
    gx = (a02 - a00) + 2.f * (a12 - a10) + (a22 - a20);
    gy = (a00 - a20) + 2.f * (a01 - a21) + (a02 - a22);
}

// ---- D0: Sobel magnitude + block max + pack {inp,tgt} + valid bits/counts ----
__global__ void prep_kernel(const float* __restrict__ inputs,
                            const float* __restrict__ targets,
                            const float* __restrict__ images,
                            float2* __restrict__ pairIT,
                            unsigned long long* __restrict__ vBits,
                            float* __restrict__ blockmax,
                            int* __restrict__ blkV) {
    int b = blockIdx.x, t = threadIdx.x;
    int i = b / BPI, bLoc = b - i * BPI;
    int gp = bLoc * 256 + t;
    int y = gp >> 10, x = gp & (W - 1);
    const float* img = images + (size_t)i * 3 * PIX;   // channel 0
    float e = 0.f;
    if (y >= 1 && y <= H - 2 && x >= 1 && x <= W - 2) {
        float gx, gy;
        sobel_g(img, y, x, gx, gy);
        e = sqrtf(gx * gx + gy * gy);
    }
    size_t off = (size_t)i * PIX + gp;
    float inv = inputs[off], tgv = targets[off];
    pairIT[off] = make_float2(inv, tgv);
    unsigned long long m = __ballot(tgv > MASKV);
    __shared__ float sm[256];
    __shared__ int sc[4];
    if ((t & 63) == 0) { vBits[off >> 6] = m; sc[t >> 6] = __popcll(m); }
    sm[t] = e;
    __syncthreads();
    for (int o = 128; o > 0; o >>= 1) {
        if (t < o) sm[t] = fmaxf(sm[t], sm[t + o]);
        __syncthreads();
    }
    if (t == 0) { blockmax[b] = sm[0]; blkV[b] = sc[0] + sc[1] + sc[2] + sc[3]; }
}

// ---- D1: redundant thr-reduce + SEGMENTED compaction (no atomics, no scan dep) ----
__global__ void compact_kernel(const float* __restrict__ images,
                               const float* __restrict__ blockmax,
                               const int* __restrict__ blkV,
                               const unsigned long long* __restrict__ vBits,
                               float2* __restrict__ anchorSeg,
                               int* __restrict__ compVSeg,
                               int* __restrict__ cntE,
                               int* __restrict__ SVg,
                               int* __restrict__ vtotG) {
    int b = blockIdx.x, t = threadIdx.x;
    int i = b / BPI, bLoc = b - i * BPI;

    // redundant per-block max-reduce of blockmax (3072 entries, L2-hot)
    __shared__ float sf[256];
    const float* bm = blockmax + i * BPI;
    float mx = 0.f;
#pragma unroll
    for (int k = 0; k < 12; k++) mx = fmaxf(mx, bm[t + k * 256]);
    sf[t] = mx;
    __syncthreads();
    for (int o = 128; o > 0; o >>= 1) {
        if (t < o) sf[t] = fmaxf(sf[t], sf[t + o]);
        __syncthreads();
    }
    float thr = 0.1f * sf[0];

    // Sobel recompute for this block's 256 pixels
    int gp = bLoc * 256 + t;
    int y = gp >> 10, x = gp & (W - 1);
    const float* img = images + (size_t)i * 3 * PIX;
    float e = 0.f, gx = 0.f, gy = 0.f;
    bool inner = (y >= 1 && y <= H - 2 && x >= 1 && x <= W - 2);
    if (inner) { sobel_g(img, y, x, gx, gy); e = sqrtf(gx * gx + gy * gy); }
    bool isE = (e >= thr);                       // border e=0: matches padded ref

    int lane = t & 63, w = t >> 6;
    unsigned long long mE = __ballot(isE);
    size_t woff = ((size_t)i * PIX + bLoc * 256) >> 6;
    unsigned long long mV = vBits[woff + w];
    __shared__ int sW[4], sWV[4];
    if (lane == 0) { sW[w] = __popcll(mE); sWV[w] = __popcll(mV); }
    __syncthreads();
    int baseE = 0, baseV = 0;
    for (int k = 0; k < w; k++) { baseE += sW[k]; baseV += sWV[k]; }
    if (t == 0) cntE[b] = sW[0] + sW[1] + sW[2] + sW[3];
    unsigned long long lm = (1ull << lane) - 1ull;
    if (isE) {                                   // segmented: slot = bLoc*256 + local rank
        float th = inner ? atan2f(gy, gx) : 0.f;
        int rank = baseE + __popcll(mE & lm);
        anchorSeg[(size_t)i * PIX + bLoc * 256 + rank] = make_float2(__int_as_float(gp), th);
    }
    if ((mV >> lane) & 1) {                      // always write; loss uses only if needed
        int rank = baseV + __popcll(mV & lm);
        compVSeg[(size_t)i * PIX + bLoc * 256 + rank] = gp;
    }

    // block 0 of each image: scan blkV -> SVg, total -> vtotG (for the general path)
    if (bLoc == 0) {
        __syncthreads();
        __shared__ int sT[256];
        const int* bv = blkV + i * BPI;
        int loc[12]; int tot = 0;
#pragma unroll
        for (int k = 0; k < 12; k++) { loc[k] = bv[t * 12 + k]; tot += loc[k]; }
        sT[t] = tot;
        __syncthreads();
        for (int o = 1; o < 256; o <<= 1) {
            int v = (t >= o) ? sT[t - o] : 0;
            __syncthreads();
            sT[t] += v;
            __syncthreads();
        }
        int run = sT[t] - tot;
        int* sv = SVg + i * BPI;
#pragma unroll
        for (int k = 0; k < 12; k++) { sv[t * 12 + k] = run; run += loc[k]; }
        if (t == 255) vtotG[i] = sT[255];
    }
}

// ---- D2: loss (redundant LDS scan of cntE + binary search; no atomics/fences) ----
__device__ __forceinline__ void pair_term(float2 a, float2 b, float& eqs, float& uns) {
    float cm = ((a.y > MASKV) ? 1.f : 0.f) * ((b.y > MASKV) ? 1.f : 0.f);
    float ratio = (a.y + 1e-6f) / (b.y + 1e-6f);
    const float HIv = 1.03f;
    const float LOv = (float)(1.0 / 1.03);
    bool eq = (ratio < HIv) && (ratio > LOv);
    if (eq) {
        float d = a.x - b.x;
        eqs += d * d * cm;
    } else {
        float label = ((ratio >= HIv) ? 1.f : 0.f) + ((ratio <= LOv) ? -1.f : 0.f);
        uns += log1pf(expf((b.x - a.x) * label)) * cm;
    }
}

__global__ void loss_kernel(const float2* __restrict__ pairIT,
                            const float2* __restrict__ anchorSeg,
                            const int* __restrict__ compVSeg,
                            const int* __restrict__ cntE,
                            const int* __restrict__ SVg,
                            const int* __restrict__ vtotG,
                            const int* __restrict__ ra, const int* __restrict__ rd,
                            const int* __restrict__ rp,
                            float2* __restrict__ partials) {
    int i = blockIdx.y, t = threadIdx.x;
    __shared__ int S[BPI];                       // 12KB: exclusive scan of cntE
    __shared__ int sT[256];
    {   // redundant scan: 12KB L2-hot load + block scan
        const int* ce = cntE + i * BPI;
        int loc[12]; int tot = 0;
#pragma unroll
        for (int k = 0; k < 12; k++) { loc[k] = ce[t * 12 + k]; tot += loc[k]; }
        sT[t] = tot;
        __syncthreads();
        for (int o = 1; o < 256; o <<= 1) {
            int v = (t >= o) ? sT[t - o] : 0;
            __syncthreads();
            sT[t] += v;
            __syncthreads();
        }
        int run = sT[t] - tot;
#pragma unroll
        for (int k = 0; k < 12; k++) { S[t * 12 + k] = run; run += loc[k]; }
        __syncthreads();
    }
    int eT = sT[255];                            // etot; >=1 always (emax passes thr)
    int vT = vtotG[i];
    int nval = (vT > 0) ? vT : 1;

    int s = blockIdx.x * 256 + t;
    const float2* pIT = pairIT + (size_t)i * PIX;

    int j = ra[(size_t)i * SNUM + s] % eT;
    int lo = 0, hi = BPI - 1;                    // largest b with S[b] <= j
#pragma unroll
    for (int k = 0; k < 12; k++) {               // 2^12 >= 3072
        int mid = (lo + hi + 1) >> 1;
        if (S[mid] <= j) lo = mid; else hi = mid - 1;
    }
    float2 ac = anchorSeg[(size_t)i * PIX + lo * 256 + (j - S[lo])];
    int anchor = __float_as_int(ac.x);
    float sv = sinf(ac.y), cv = cosf(ac.y);
    int row_a = anchor >> 10, col_a = anchor & (W - 1);

    int pix4[4];
#pragma unroll
    for (int k = 0; k < 4; k++) {
        int r = rd[((size_t)i * 4 + k) * SNUM + s];
        float dist = ((float)r + 2.0f) * ((k < 2) ? -1.f : 1.f);
        int cc = col_a + (int)rintf(dist * cv);  // round-half-even = jnp.round
        int rr = row_a + (int)rintf(dist * sv);
        cc = min(max(cc, 0), W - 1);
        rr = min(max(rr, 0), H - 1);
        pix4[k] = (rr << 10) | cc;
    }
    int2 rr2 = *(const int2*)(rp + (size_t)i * 2 * SNUM + 2 * s);
    int r0 = rr2.x % nval, r1 = rr2.y % nval;
    int A, B;
    if ((vT == PIX) || (vT == 0)) {              // identity compaction cases
        A = r0; B = r1;
    } else {                                     // general path: search SVg (L2-hot)
        const int* SV = SVg + i * BPI;
        int lo2 = 0, hi2 = BPI - 1;
        int lo3 = 0, hi3 = BPI - 1;
#pragma unroll
        for (int k = 0; k < 12; k++) {
            int m2 = (lo2 + hi2 + 1) >> 1;
            if (SV[m2] <= r0) lo2 = m2; else hi2 = m2 - 1;
            int m3 = (lo3 + hi3 + 1) >> 1;
            if (SV[m3] <= r1) lo3 = m3; else hi3 = m3 - 1;
        }
        A = compVSeg[(size_t)i * PIX + lo2 * 256 + (r0 - SV[lo2])];
        B = compVSeg[(size_t)i * PIX + lo3 * 256 + (r1 - SV[lo3])];
    }

    float2 a0 = pIT[pix4[0]], a1 = pIT[pix4[1]], a2 = pIT[pix4[2]], a3 = pIT[pix4[3]];
    float2 b0 = pIT[A], b1 = pIT[B];
    float eqs = 0.f, uns = 0.f;
    pair_term(a0, a1, eqs, uns);
    pair_term(a1, a2, eqs, uns);
    pair_term(a2, a3, eqs, uns);
    pair_term(b0, b1, eqs, uns);

    __shared__ float sEq[256], sUn[256];
    sEq[t] = eqs; sUn[t] = uns;
    __syncthreads();
    for (int o = 128; o > 0; o >>= 1) {
        if (t < o) { sEq[t] += sEq[t + o]; sUn[t] += sUn[t + o]; }
        __syncthreads();
    }
    if (t == 0)
        partials[i * 512 + blockIdx.x] = make_float2(sEq[0], sUn[0]);
}

// ---- D3: final reduce ----
__global__ void final_kernel(const float2* __restrict__ partials, float* __restrict__ out) {
    int t = threadIdx.x;                         // 256 threads, 2048 partials
    double acc = 0.0;
#pragma unroll
    for (int k = 0; k < 8; k++) {
        float2 p = partials[t + k * 256];
        acc += (double)p.x + (double)p.y;
    }
    __shared__ double sm[256];
    sm[t] = acc;
    __syncthreads();
    for (int o = 128; o > 0; o >>= 1) {
        if (t < o) sm[t] += sm[t + o];
        __syncthreads();
    }
    if (t == 0) {
        double denom = 4.0 * (double)SNUM;       // each mean over 4*S terms; ALPHA=1
        out[0] = (float)(sm[0] / denom / (double)NIMG);
    }
}

extern "C" void kernel_launch(void* const* d_in, const int* in_sizes, int n_in,
                              void* d_out, int out_size, void* d_ws, size_t ws_size,
                              hipStream_t stream) {
    const float* inputs  = (const float*)d_in[0];
    const float* targets = (const float*)d_in[1];
    const float* images  = (const float*)d_in[2];
    const int* ra = (const int*)d_in[3];
    const int* rd = (const int*)d_in[4];
    const int* rp = (const int*)d_in[5];
    float* out = (float*)d_out;

    char* ws = (char*)d_ws;
    int*      vtotG    = (int*)ws;                         // [4]
    float*    blockmax = (float*)(ws + 1024);              // [12288] = 48KB
    int*      blkV     = (int*)(ws + 50176);               // [12288] = 48KB
    int*      cntE     = (int*)(ws + 99328);               // [12288] = 48KB
    int*      SVg      = (int*)(ws + 148480);              // [12288] = 48KB
    float2*   partials = (float2*)(ws + 197632);           // [2048] = 16KB
    unsigned long long* vBits = (unsigned long long*)(ws + 262144);   // 384KB
    float2*   pairIT   = (float2*)(ws + 1048576);          // 25.2MB
    float2*   anchorSeg= (float2*)(ws + 26214400);         // 25.2MB (segmented)
    int*      compVSeg = (int*)(ws + 51380224);            // 12.6MB (segmented)
    // total ~61MB (same footprint as round 6); every word written before read

    prep_kernel<<<NB, 256, 0, stream>>>(inputs, targets, images,
                                        pairIT, vBits, blockmax, blkV);
    compact_kernel<<<NB, 256, 0, stream>>>(images, blockmax, blkV, vBits,
                                           anchorSeg, compVSeg, cntE, SVg, vtotG);
    loss_kernel<<<dim3(512, NIMG), 256, 0, stream>>>(pairIT, anchorSeg, compVSeg,
                                                     cntE, SVg, vtotG,
                                                     ra, rd, rp, partials);
    final_kernel<<<1, 256, 0, stream>>>(partials, out);
}